// Round 6
// baseline (149.714 us; speedup 1.0000x reference)
//
#include <hip/hip_runtime.h>

#define NN 100000
#define NE 1600000
#define DIN 128
#define DOUT 32
#define NBUK 391     // ceil(NN/256) buckets of 256 nodes
#define FILLB 196    // edge chunks
#define CHUNK 8192   // edges per chunk (196*8192 >= NE)
#define CAP 8192     // max records per bucket staged in LDS (mean 4092, sd ~64)

typedef unsigned short ushort_t;
typedef unsigned int uint_t;

static __device__ __forceinline__ ushort_t f2bf(float f) {
    uint_t u = __float_as_uint(f);
    u += 0x7fffu + ((u >> 16) & 1u);   // round-to-nearest-even
    return (ushort_t)(u >> 16);
}
static __device__ __forceinline__ float bfl(uint_t p) { return __uint_as_float(p << 16); }
static __device__ __forceinline__ float bfh(uint_t p) { return __uint_as_float(p & 0xffff0000u); }

// ===========================================================================
// k1: per-(chunk,bucket) histogram -> histmat[FILLB][NBUK]. LDS atomics only.
// ===========================================================================
__global__ __launch_bounds__(256)
void hist_kernel(const int* __restrict__ col, int* __restrict__ histmat) {
    __shared__ int h[NBUK];
    int t = threadIdx.x, blk = blockIdx.x;
    for (int b = t; b < NBUK; b += 256) h[b] = 0;
    __syncthreads();
    int e0 = blk * CHUNK, emax = min(e0 + CHUNK, NE);
    for (int e = e0 + t; e < emax; e += 256) atomicAdd(&h[col[e] >> 8], 1);
    __syncthreads();
    for (int b = t; b < NBUK; b += 256) histmat[(size_t)blk * NBUK + b] = h[b];
}

// ===========================================================================
// k2a: per-bucket exclusive scan over the 196 chunks (in place) + bucket totals
// ===========================================================================
__global__ __launch_bounds__(256)
void colscan_kernel(int* __restrict__ histmat, int* __restrict__ bsum) {
    __shared__ int s[256];
    int b = blockIdx.x, t = threadIdx.x;
    int v = (t < FILLB) ? histmat[(size_t)t * NBUK + b] : 0;
    s[t] = v;
    __syncthreads();
    for (int off = 1; off < 256; off <<= 1) {
        int u = (t >= off) ? s[t - off] : 0;
        __syncthreads();
        s[t] += u;
        __syncthreads();
    }
    if (t < FILLB) histmat[(size_t)t * NBUK + b] = s[t] - v;  // exclusive
    if (t == FILLB - 1) bsum[b] = s[t];
}

// ===========================================================================
// k2b: exclusive scan of bucket totals -> base[NBUK+1]
// ===========================================================================
__global__ void bscan_kernel(const int* __restrict__ bsum, int* __restrict__ base) {
    __shared__ int s[512];
    int t = threadIdx.x;
    int own = (t < NBUK) ? bsum[t] : 0;
    s[t] = own;
    __syncthreads();
    for (int off = 1; off < 512; off <<= 1) {
        int v = (t >= off) ? s[t - off] : 0;
        __syncthreads();
        s[t] += v;
        __syncthreads();
    }
    if (t < NBUK) {
        base[t] = s[t] - own;
        if (t == NBUK - 1) base[NBUK] = s[t];
    }
}

// ===========================================================================
// k3: fill records at deterministic positions (LDS cursors, no global atomics)
// record = (row << 8) | (col & 255)
// ===========================================================================
__global__ __launch_bounds__(256)
void fill_kernel(const int* __restrict__ row, const int* __restrict__ col,
                 const int* __restrict__ base, const int* __restrict__ histmat,
                 unsigned int* __restrict__ records) {
    __shared__ int lcur[NBUK];
    int t = threadIdx.x, blk = blockIdx.x;
    for (int b = t; b < NBUK; b += 256)
        lcur[b] = base[b] + histmat[(size_t)blk * NBUK + b];
    __syncthreads();
    int e0 = blk * CHUNK, emax = min(e0 + CHUNK, NE);
    for (int e = e0 + t; e < emax; e += 256) {
        int c = col[e];
        int slot = atomicAdd(&lcur[c >> 8], 1);
        records[slot] = ((unsigned int)row[e] << 8) | (unsigned int)(c & 255);
    }
}

// ===========================================================================
// k4: per-bucket sort (records -> grouped by node, in place), + deg -> dis,
// + per-node CSR offsets. All writes block-local / coalesced.
// ===========================================================================
__global__ __launch_bounds__(256)
void sort_kernel(const int* __restrict__ base, unsigned int* __restrict__ records,
                 float* __restrict__ dis, int* __restrict__ offs) {
    __shared__ unsigned int stage[CAP];  // 32 KB
    __shared__ int hist[256];
    __shared__ int sc[256];
    __shared__ int lcur[256];
    int b = blockIdx.x, t = threadIdx.x;
    int s = base[b], e = base[b + 1];
    int cnt = e - s;
    hist[t] = 0;
    for (int j = t; j < cnt; j += 256) stage[j] = records[s + j];
    __syncthreads();
    for (int j = t; j < cnt; j += 256) atomicAdd(&hist[stage[j] & 255u], 1);
    __syncthreads();
    int d = hist[t];
    sc[t] = d;
    __syncthreads();
    for (int off = 1; off < 256; off <<= 1) {
        int u = (t >= off) ? sc[t - off] : 0;
        __syncthreads();
        sc[t] += u;
        __syncthreads();
    }
    int excl = sc[t] - d;
    int n = (b << 8) + t;
    if (n < NN) {
        dis[n] = rsqrtf((float)(d + 1));
        offs[n] = s + excl;
        if (n == NN - 1) offs[NN] = e;
    }
    lcur[t] = excl;
    __syncthreads();
    for (int j = t; j < cnt; j += 256) {
        unsigned int rec = stage[j];
        int slot = atomicAdd(&lcur[rec & 255u], 1);
        records[s + slot] = rec >> 8;  // now plain src row id
    }
}

// ===========================================================================
// k5: xwsb[r] = bf16( (x[r] @ W) * dis[r] )
// 4 threads per row, 8 outputs each -> 6250 waves (~6/SIMD) for latency hiding.
// W is 16 KB, L1-resident; 4-lane address dedup on both x and W loads.
// ===========================================================================
__global__ __launch_bounds__(256)
void xw_kernel(const float* __restrict__ x, const float* __restrict__ W,
               const float* __restrict__ dis, ushort_t* __restrict__ xwsb) {
    int g = blockIdx.x * 256 + threadIdx.x;
    int r = g >> 2;
    int q = g & 3;                 // output group: dims q*8 .. q*8+7
    if (r >= NN) return;
    float dr = dis[r];
    const float4* __restrict__ xr = (const float4*)(x + (size_t)r * DIN);
    const float* __restrict__ Wq = W + (q << 3);
    float4 a0 = make_float4(0.f, 0.f, 0.f, 0.f);
    float4 a1 = make_float4(0.f, 0.f, 0.f, 0.f);
#pragma unroll 2
    for (int kq = 0; kq < DIN / 4; ++kq) {
        float4 xv = xr[kq];
        const float* Wk = Wq + (size_t)(kq * 4) * DOUT;
        float4 w00 = *(const float4*)(Wk);
        float4 w01 = *(const float4*)(Wk + 4);
        float4 w10 = *(const float4*)(Wk + DOUT);
        float4 w11 = *(const float4*)(Wk + DOUT + 4);
        float4 w20 = *(const float4*)(Wk + 2 * DOUT);
        float4 w21 = *(const float4*)(Wk + 2 * DOUT + 4);
        float4 w30 = *(const float4*)(Wk + 3 * DOUT);
        float4 w31 = *(const float4*)(Wk + 3 * DOUT + 4);
        a0.x += xv.x * w00.x + xv.y * w10.x + xv.z * w20.x + xv.w * w30.x;
        a0.y += xv.x * w00.y + xv.y * w10.y + xv.z * w20.y + xv.w * w30.y;
        a0.z += xv.x * w00.z + xv.y * w10.z + xv.z * w20.z + xv.w * w30.z;
        a0.w += xv.x * w00.w + xv.y * w10.w + xv.z * w20.w + xv.w * w30.w;
        a1.x += xv.x * w01.x + xv.y * w11.x + xv.z * w21.x + xv.w * w31.x;
        a1.y += xv.x * w01.y + xv.y * w11.y + xv.z * w21.y + xv.w * w31.y;
        a1.z += xv.x * w01.z + xv.y * w11.z + xv.z * w21.z + xv.w * w31.z;
        a1.w += xv.x * w01.w + xv.y * w11.w + xv.z * w21.w + xv.w * w31.w;
    }
    a0.x *= dr; a0.y *= dr; a0.z *= dr; a0.w *= dr;
    a1.x *= dr; a1.y *= dr; a1.z *= dr; a1.w *= dr;
    uint_t p0 = (uint_t)f2bf(a0.x) | ((uint_t)f2bf(a0.y) << 16);
    uint_t p1 = (uint_t)f2bf(a0.z) | ((uint_t)f2bf(a0.w) << 16);
    uint_t p2 = (uint_t)f2bf(a1.x) | ((uint_t)f2bf(a1.y) << 16);
    uint_t p3 = (uint_t)f2bf(a1.z) | ((uint_t)f2bf(a1.w) << 16);
    *(uint4*)(xwsb + (size_t)r * DOUT + (q << 3)) = make_uint4(p0, p1, p2, p3);
}

// ===========================================================================
// k6: per-node wave gather over bf16 rows (64 B = 1 line per edge).
// lane = (slot 0..15, dhalf 0..3): 16 edges/iter, uint4 gather per lane;
// masked tail lanes dedup to one line. shfl_xor(4/8/16/32) reduce.
// ===========================================================================
__global__ __launch_bounds__(256)
void aggregate_kernel(const int* __restrict__ offs, const int* __restrict__ srcs,
                      const float* __restrict__ dis, const ushort_t* __restrict__ xwsb,
                      const float* __restrict__ bias, float* __restrict__ out) {
    int wid = (int)((blockIdx.x * blockDim.x + threadIdx.x) >> 6);
    if (wid >= NN) return;
    int lane = threadIdx.x & 63;
    int slot = lane >> 2;        // 0..15 edge slot
    int d0 = (lane & 3) << 3;    // 0,8,16,24
    int s = offs[wid], e = offs[wid + 1];
    float a[8] = {0.f, 0.f, 0.f, 0.f, 0.f, 0.f, 0.f, 0.f};
#pragma unroll 2
    for (int i = s; i < e; i += 16) {
        int j = i + slot;
        bool ok = j < e;
        int r = srcs[ok ? j : e - 1];
        uint4 u = *(const uint4*)(xwsb + (size_t)r * DOUT + d0);
        float m = ok ? 1.f : 0.f;
        a[0] += m * bfl(u.x); a[1] += m * bfh(u.x);
        a[2] += m * bfl(u.y); a[3] += m * bfh(u.y);
        a[4] += m * bfl(u.z); a[5] += m * bfh(u.z);
        a[6] += m * bfl(u.w); a[7] += m * bfh(u.w);
    }
#pragma unroll
    for (int msk = 4; msk <= 32; msk <<= 1) {
#pragma unroll
        for (int v = 0; v < 8; ++v) a[v] += __shfl_xor(a[v], msk, 64);
    }
    if (slot == 0) {
        uint4 su = *(const uint4*)(xwsb + (size_t)wid * DOUT + d0);  // self-loop
        a[0] += bfl(su.x); a[1] += bfh(su.x);
        a[2] += bfl(su.y); a[3] += bfh(su.y);
        a[4] += bfl(su.z); a[5] += bfh(su.z);
        a[6] += bfl(su.w); a[7] += bfh(su.w);
        float dc = dis[wid];
        float4 b0 = *(const float4*)(bias + d0);
        float4 b1 = *(const float4*)(bias + d0 + 4);
        float4 o0, o1;
        o0.x = dc * a[0] + b0.x; o0.y = dc * a[1] + b0.y;
        o0.z = dc * a[2] + b0.z; o0.w = dc * a[3] + b0.w;
        o1.x = dc * a[4] + b1.x; o1.y = dc * a[5] + b1.y;
        o1.z = dc * a[6] + b1.z; o1.w = dc * a[7] + b1.w;
        *(float4*)(out + (size_t)wid * DOUT + d0) = o0;
        *(float4*)(out + (size_t)wid * DOUT + d0 + 4) = o1;
    }
}

// ===========================================================================
// Fallback path (R1) if workspace is too small
// ===========================================================================
__global__ void deg_count_kernel(const int* __restrict__ col, int* __restrict__ deg) {
    int e = blockIdx.x * blockDim.x + threadIdx.x;
    if (e < NE) atomicAdd(&deg[col[e]], 1);
}
__global__ void dis_kernel(const int* __restrict__ deg, float* __restrict__ dis) {
    int i = blockIdx.x * blockDim.x + threadIdx.x;
    if (i < NN) dis[i] = rsqrtf((float)(deg[i] + 1));
}
__global__ void xw_init_kernel(const float* __restrict__ x, const float* __restrict__ W,
                               const float* __restrict__ b, const float* __restrict__ dis,
                               float* __restrict__ xw, float* __restrict__ out) {
    __shared__ float Ws[DIN * DOUT];
    for (int i = threadIdx.x; i < DIN * DOUT; i += blockDim.x) Ws[i] = W[i];
    __syncthreads();
    int idx = blockIdx.x * blockDim.x + threadIdx.x;
    if (idx >= NN * DOUT) return;
    int n = idx >> 5;
    int d = idx & (DOUT - 1);
    const float* xr = x + (long long)n * DIN;
    float acc = 0.f;
#pragma unroll
    for (int k = 0; k < DIN; ++k) acc += xr[k] * Ws[k * DOUT + d];
    xw[idx] = acc;
    float di = dis[n];
    out[idx] = di * di * acc + b[d];
}
__global__ void scatter_kernel(const int* __restrict__ row, const int* __restrict__ col,
                               const float* __restrict__ dis, const float* __restrict__ xw,
                               float* __restrict__ out) {
    long long idx = (long long)blockIdx.x * blockDim.x + threadIdx.x;
    if (idx >= (long long)NE * DOUT) return;
    int e = (int)(idx >> 5);
    int d = (int)(idx & (DOUT - 1));
    int r = row[e];
    int c = col[e];
    atomicAdd(&out[c * DOUT + d], dis[r] * dis[c] * xw[r * DOUT + d]);
}

// ===========================================================================
extern "C" void kernel_launch(void* const* d_in, const int* in_sizes, int n_in,
                              void* d_out, int out_size, void* d_ws, size_t ws_size,
                              hipStream_t stream) {
    const float* x  = (const float*)d_in[0];
    const int*   ei = (const int*)d_in[1];
    const float* W  = (const float*)d_in[2];
    const float* b  = (const float*)d_in[3];
    float* out = (float*)d_out;

    const int* row = ei;       // edge_index[0] = source
    const int* col = ei + NE;  // edge_index[1] = target

    char* ws = (char*)d_ws;
    int*          histmat = (int*)(ws + 0);          //   306,544 B
    int*          bsum    = (int*)(ws + 306560);     //     1,564 B
    int*          base    = (int*)(ws + 308224);     //     1,568 B (NBUK+1)
    int*          offs    = (int*)(ws + 309888);     //   400,004 B (NN+1)
    float*        dis     = (float*)(ws + 710016);   //   400,000 B
    unsigned int* records = (unsigned int*)(ws + 1110144);  // 6,400,000 B
    ushort_t*     xwsb    = (ushort_t*)(ws + 7510144);      // 6,400,000 B
    const size_t WS_NEEDED = 13910144ull;

    if (ws_size >= WS_NEEDED) {
        hist_kernel<<<FILLB, 256, 0, stream>>>(col, histmat);
        colscan_kernel<<<NBUK, 256, 0, stream>>>(histmat, bsum);
        bscan_kernel<<<1, 512, 0, stream>>>(bsum, base);
        fill_kernel<<<FILLB, 256, 0, stream>>>(row, col, base, histmat, records);
        sort_kernel<<<NBUK, 256, 0, stream>>>(base, records, dis, offs);
        {
            long long threads = (long long)NN * 4;
            int bl = (int)((threads + 255) / 256);
            xw_kernel<<<bl, 256, 0, stream>>>(x, W, dis, xwsb);
        }
        {
            long long threads = (long long)NN * 64;
            int bl = (int)((threads + 255) / 256);
            aggregate_kernel<<<bl, 256, 0, stream>>>(offs, (const int*)records, dis, xwsb, b, out);
        }
    } else {
        // fallback: atomic scatter path
        int* deg = (int*)(ws + 0);
        float* dis2 = (float*)(ws + 400128);
        float* xw = (float*)(ws + 800256);
        hipMemsetAsync(deg, 0, NN * sizeof(int), stream);
        {
            int th = 256, bl = (NE + th - 1) / th;
            deg_count_kernel<<<bl, th, 0, stream>>>(col, deg);
        }
        {
            int th = 256, bl = (NN + th - 1) / th;
            dis_kernel<<<bl, th, 0, stream>>>(deg, dis2);
        }
        {
            long long total = (long long)NN * DOUT;
            int bl = (int)((total + 255) / 256);
            xw_init_kernel<<<bl, 256, 0, stream>>>(x, W, b, dis2, xw, out);
        }
        {
            long long total = (long long)NE * DOUT;
            int bl = (int)((total + 255) / 256);
            scatter_kernel<<<bl, 256, 0, stream>>>(row, col, dis2, xw, out);
        }
    }
}

// Round 7
// 137.963 us; speedup vs baseline: 1.0852x; 1.0852x over previous
//
#include <hip/hip_runtime.h>

#define NN 100000
#define NE 1600000
#define DIN 128
#define DOUT 32
#define NBUK 391     // ceil(NN/256) buckets of 256 nodes
#define FILLB 196    // edge chunks
#define CHUNK 8192   // edges per chunk (196*8192 >= NE)
#define CAP 8192     // max records per bucket staged in LDS (mean 4092, sd ~64)

typedef unsigned short ushort_t;
typedef unsigned int uint_t;

static __device__ __forceinline__ ushort_t f2bf(float f) {
    uint_t u = __float_as_uint(f);
    u += 0x7fffu + ((u >> 16) & 1u);   // round-to-nearest-even
    return (ushort_t)(u >> 16);
}
static __device__ __forceinline__ float bfl(uint_t p) { return __uint_as_float(p << 16); }
static __device__ __forceinline__ float bfh(uint_t p) { return __uint_as_float(p & 0xffff0000u); }

// ===========================================================================
// k1: per-(chunk,bucket) histogram -> histmat[FILLB][NBUK]. LDS atomics only.
// ===========================================================================
__global__ __launch_bounds__(256)
void hist_kernel(const int* __restrict__ col, int* __restrict__ histmat) {
    __shared__ int h[NBUK];
    int t = threadIdx.x, blk = blockIdx.x;
    for (int b = t; b < NBUK; b += 256) h[b] = 0;
    __syncthreads();
    int e0 = blk * CHUNK, emax = min(e0 + CHUNK, NE);
    for (int e = e0 + t; e < emax; e += 256) atomicAdd(&h[col[e] >> 8], 1);
    __syncthreads();
    for (int b = t; b < NBUK; b += 256) histmat[(size_t)blk * NBUK + b] = h[b];
}

// ===========================================================================
// k2a: per-bucket exclusive scan over the 196 chunks (in place) + bucket totals
// ===========================================================================
__global__ __launch_bounds__(256)
void colscan_kernel(int* __restrict__ histmat, int* __restrict__ bsum) {
    __shared__ int s[256];
    int b = blockIdx.x, t = threadIdx.x;
    int v = (t < FILLB) ? histmat[(size_t)t * NBUK + b] : 0;
    s[t] = v;
    __syncthreads();
    for (int off = 1; off < 256; off <<= 1) {
        int u = (t >= off) ? s[t - off] : 0;
        __syncthreads();
        s[t] += u;
        __syncthreads();
    }
    if (t < FILLB) histmat[(size_t)t * NBUK + b] = s[t] - v;  // exclusive
    if (t == FILLB - 1) bsum[b] = s[t];
}

// ===========================================================================
// k2b: exclusive scan of bucket totals -> base[NBUK+1]
// ===========================================================================
__global__ void bscan_kernel(const int* __restrict__ bsum, int* __restrict__ base) {
    __shared__ int s[512];
    int t = threadIdx.x;
    int own = (t < NBUK) ? bsum[t] : 0;
    s[t] = own;
    __syncthreads();
    for (int off = 1; off < 512; off <<= 1) {
        int v = (t >= off) ? s[t - off] : 0;
        __syncthreads();
        s[t] += v;
        __syncthreads();
    }
    if (t < NBUK) {
        base[t] = s[t] - own;
        if (t == NBUK - 1) base[NBUK] = s[t];
    }
}

// ===========================================================================
// k3: fill records at deterministic positions (LDS cursors, no global atomics)
// record = (row << 8) | (col & 255)
// ===========================================================================
__global__ __launch_bounds__(256)
void fill_kernel(const int* __restrict__ row, const int* __restrict__ col,
                 const int* __restrict__ base, const int* __restrict__ histmat,
                 unsigned int* __restrict__ records) {
    __shared__ int lcur[NBUK];
    int t = threadIdx.x, blk = blockIdx.x;
    for (int b = t; b < NBUK; b += 256)
        lcur[b] = base[b] + histmat[(size_t)blk * NBUK + b];
    __syncthreads();
    int e0 = blk * CHUNK, emax = min(e0 + CHUNK, NE);
    for (int e = e0 + t; e < emax; e += 256) {
        int c = col[e];
        int slot = atomicAdd(&lcur[c >> 8], 1);
        records[slot] = ((unsigned int)row[e] << 8) | (unsigned int)(c & 255);
    }
}

// ===========================================================================
// k4: per-bucket sort (records -> grouped by node, in place), + deg -> dis,
// + per-node CSR offsets. All writes block-local / coalesced.
// ===========================================================================
__global__ __launch_bounds__(256)
void sort_kernel(const int* __restrict__ base, unsigned int* __restrict__ records,
                 float* __restrict__ dis, int* __restrict__ offs) {
    __shared__ unsigned int stage[CAP];  // 32 KB
    __shared__ int hist[256];
    __shared__ int sc[256];
    __shared__ int lcur[256];
    int b = blockIdx.x, t = threadIdx.x;
    int s = base[b], e = base[b + 1];
    int cnt = e - s;
    hist[t] = 0;
    for (int j = t; j < cnt; j += 256) stage[j] = records[s + j];
    __syncthreads();
    for (int j = t; j < cnt; j += 256) atomicAdd(&hist[stage[j] & 255u], 1);
    __syncthreads();
    int d = hist[t];
    sc[t] = d;
    __syncthreads();
    for (int off = 1; off < 256; off <<= 1) {
        int u = (t >= off) ? sc[t - off] : 0;
        __syncthreads();
        sc[t] += u;
        __syncthreads();
    }
    int excl = sc[t] - d;
    int n = (b << 8) + t;
    if (n < NN) {
        dis[n] = rsqrtf((float)(d + 1));
        offs[n] = s + excl;
        if (n == NN - 1) offs[NN] = e;
    }
    lcur[t] = excl;
    __syncthreads();
    for (int j = t; j < cnt; j += 256) {
        unsigned int rec = stage[j];
        int slot = atomicAdd(&lcur[rec & 255u], 1);
        records[s + slot] = rec >> 8;  // now plain src row id
    }
}

// ===========================================================================
// k5: xwsb[r] = bf16( (x[r] @ W) * dis[r] )
// Block = 4 waves over 64 rows; wave w computes k-quarter [w*32, w*32+32) for
// all 64 rows (lane = row). W addresses are wave-uniform (readfirstlane ->
// SGPR -> s_load const-cache broadcast); x is per-lane float4 stream.
// Partials combined via LDS [w][d][row] (conflict-free both directions).
// 1563 blocks = 6252 waves for TLP.
// ===========================================================================
__global__ __launch_bounds__(256)
void xw_kernel(const float* __restrict__ x, const float* __restrict__ W,
               const float* __restrict__ dis, ushort_t* __restrict__ xwsb) {
    __shared__ float part[4][DOUT][64];   // 32 KB
    int t = threadIdx.x;
    int w = t >> 6;                       // wave id = k-quarter
    int l = t & 63;                       // row within block
    int r0 = blockIdx.x * 64;
    int r = r0 + l;
    bool valid = r < NN;
    int wu = __builtin_amdgcn_readfirstlane(w);   // force SGPR
    const float* __restrict__ xr = x + (size_t)r * DIN + wu * 32;
    float a[DOUT];
#pragma unroll
    for (int d = 0; d < DOUT; ++d) a[d] = 0.f;

#pragma unroll
    for (int kq = 0; kq < 8; ++kq) {
        float4 xv = valid ? *(const float4*)(xr + kq * 4)
                          : make_float4(0.f, 0.f, 0.f, 0.f);
        const float* __restrict__ Wk = W + (size_t)(wu * 32 + kq * 4) * DOUT;
#pragma unroll
        for (int dq = 0; dq < 8; ++dq) {
            float4 w0 = *(const float4*)(Wk + dq * 4);             // k+0
            float4 w1 = *(const float4*)(Wk + DOUT + dq * 4);      // k+1
            float4 w2 = *(const float4*)(Wk + 2 * DOUT + dq * 4);  // k+2
            float4 w3 = *(const float4*)(Wk + 3 * DOUT + dq * 4);  // k+3
            a[dq * 4 + 0] += xv.x * w0.x + xv.y * w1.x + xv.z * w2.x + xv.w * w3.x;
            a[dq * 4 + 1] += xv.x * w0.y + xv.y * w1.y + xv.z * w2.y + xv.w * w3.y;
            a[dq * 4 + 2] += xv.x * w0.z + xv.y * w1.z + xv.z * w2.z + xv.w * w3.z;
            a[dq * 4 + 3] += xv.x * w0.w + xv.y * w1.w + xv.z * w2.w + xv.w * w3.w;
        }
    }
    // write partials: fixed (w,d) per instruction, lanes = consecutive rows
#pragma unroll
    for (int d = 0; d < DOUT; ++d) part[w][d][l] = a[d];
    __syncthreads();

    // combine: wave w2 handles dim-quarter dq = w2, lane = row (conflict-free)
    int dq = w;       // dims dq*8 .. dq*8+7
    int rr = l;
    int rout = r0 + rr;
    if (rout < NN) {
        float v[8];
#pragma unroll
        for (int j = 0; j < 8; ++j)
            v[j] = part[0][dq * 8 + j][rr] + part[1][dq * 8 + j][rr] +
                   part[2][dq * 8 + j][rr] + part[3][dq * 8 + j][rr];
        float dr = dis[rout];
#pragma unroll
        for (int j = 0; j < 8; ++j) v[j] *= dr;
        uint_t p0 = (uint_t)f2bf(v[0]) | ((uint_t)f2bf(v[1]) << 16);
        uint_t p1 = (uint_t)f2bf(v[2]) | ((uint_t)f2bf(v[3]) << 16);
        uint_t p2 = (uint_t)f2bf(v[4]) | ((uint_t)f2bf(v[5]) << 16);
        uint_t p3 = (uint_t)f2bf(v[6]) | ((uint_t)f2bf(v[7]) << 16);
        *(uint4*)(xwsb + (size_t)rout * DOUT + dq * 8) = make_uint4(p0, p1, p2, p3);
    }
}

// ===========================================================================
// k6: per-node wave gather over bf16 rows (64 B = 1 line per edge).
// lane = (slot 0..15, dhalf 0..3): 16 edges/iter, uint4 gather per lane;
// masked tail lanes dedup to one line. shfl_xor(4/8/16/32) reduce.
// ===========================================================================
__global__ __launch_bounds__(256)
void aggregate_kernel(const int* __restrict__ offs, const int* __restrict__ srcs,
                      const float* __restrict__ dis, const ushort_t* __restrict__ xwsb,
                      const float* __restrict__ bias, float* __restrict__ out) {
    int wid = (int)((blockIdx.x * blockDim.x + threadIdx.x) >> 6);
    if (wid >= NN) return;
    int lane = threadIdx.x & 63;
    int slot = lane >> 2;        // 0..15 edge slot
    int d0 = (lane & 3) << 3;    // 0,8,16,24
    int s = offs[wid], e = offs[wid + 1];
    float a[8] = {0.f, 0.f, 0.f, 0.f, 0.f, 0.f, 0.f, 0.f};
#pragma unroll 2
    for (int i = s; i < e; i += 16) {
        int j = i + slot;
        bool ok = j < e;
        int r = srcs[ok ? j : e - 1];
        uint4 u = *(const uint4*)(xwsb + (size_t)r * DOUT + d0);
        float m = ok ? 1.f : 0.f;
        a[0] += m * bfl(u.x); a[1] += m * bfh(u.x);
        a[2] += m * bfl(u.y); a[3] += m * bfh(u.y);
        a[4] += m * bfl(u.z); a[5] += m * bfh(u.z);
        a[6] += m * bfl(u.w); a[7] += m * bfh(u.w);
    }
#pragma unroll
    for (int msk = 4; msk <= 32; msk <<= 1) {
#pragma unroll
        for (int v = 0; v < 8; ++v) a[v] += __shfl_xor(a[v], msk, 64);
    }
    if (slot == 0) {
        uint4 su = *(const uint4*)(xwsb + (size_t)wid * DOUT + d0);  // self-loop
        a[0] += bfl(su.x); a[1] += bfh(su.x);
        a[2] += bfl(su.y); a[3] += bfh(su.y);
        a[4] += bfl(su.z); a[5] += bfh(su.z);
        a[6] += bfl(su.w); a[7] += bfh(su.w);
        float dc = dis[wid];
        float4 b0 = *(const float4*)(bias + d0);
        float4 b1 = *(const float4*)(bias + d0 + 4);
        float4 o0, o1;
        o0.x = dc * a[0] + b0.x; o0.y = dc * a[1] + b0.y;
        o0.z = dc * a[2] + b0.z; o0.w = dc * a[3] + b0.w;
        o1.x = dc * a[4] + b1.x; o1.y = dc * a[5] + b1.y;
        o1.z = dc * a[6] + b1.z; o1.w = dc * a[7] + b1.w;
        *(float4*)(out + (size_t)wid * DOUT + d0) = o0;
        *(float4*)(out + (size_t)wid * DOUT + d0 + 4) = o1;
    }
}

// ===========================================================================
// Fallback path (R1) if workspace is too small
// ===========================================================================
__global__ void deg_count_kernel(const int* __restrict__ col, int* __restrict__ deg) {
    int e = blockIdx.x * blockDim.x + threadIdx.x;
    if (e < NE) atomicAdd(&deg[col[e]], 1);
}
__global__ void dis_kernel(const int* __restrict__ deg, float* __restrict__ dis) {
    int i = blockIdx.x * blockDim.x + threadIdx.x;
    if (i < NN) dis[i] = rsqrtf((float)(deg[i] + 1));
}
__global__ void xw_init_kernel(const float* __restrict__ x, const float* __restrict__ W,
                               const float* __restrict__ b, const float* __restrict__ dis,
                               float* __restrict__ xw, float* __restrict__ out) {
    __shared__ float Ws[DIN * DOUT];
    for (int i = threadIdx.x; i < DIN * DOUT; i += blockDim.x) Ws[i] = W[i];
    __syncthreads();
    int idx = blockIdx.x * blockDim.x + threadIdx.x;
    if (idx >= NN * DOUT) return;
    int n = idx >> 5;
    int d = idx & (DOUT - 1);
    const float* xr = x + (long long)n * DIN;
    float acc = 0.f;
#pragma unroll
    for (int k = 0; k < DIN; ++k) acc += xr[k] * Ws[k * DOUT + d];
    xw[idx] = acc;
    float di = dis[n];
    out[idx] = di * di * acc + b[d];
}
__global__ void scatter_kernel(const int* __restrict__ row, const int* __restrict__ col,
                               const float* __restrict__ dis, const float* __restrict__ xw,
                               float* __restrict__ out) {
    long long idx = (long long)blockIdx.x * blockDim.x + threadIdx.x;
    if (idx >= (long long)NE * DOUT) return;
    int e = (int)(idx >> 5);
    int d = (int)(idx & (DOUT - 1));
    int r = row[e];
    int c = col[e];
    atomicAdd(&out[c * DOUT + d], dis[r] * dis[c] * xw[r * DOUT + d]);
}

// ===========================================================================
extern "C" void kernel_launch(void* const* d_in, const int* in_sizes, int n_in,
                              void* d_out, int out_size, void* d_ws, size_t ws_size,
                              hipStream_t stream) {
    const float* x  = (const float*)d_in[0];
    const int*   ei = (const int*)d_in[1];
    const float* W  = (const float*)d_in[2];
    const float* b  = (const float*)d_in[3];
    float* out = (float*)d_out;

    const int* row = ei;       // edge_index[0] = source
    const int* col = ei + NE;  // edge_index[1] = target

    char* ws = (char*)d_ws;
    int*          histmat = (int*)(ws + 0);          //   306,544 B
    int*          bsum    = (int*)(ws + 306560);     //     1,564 B
    int*          base    = (int*)(ws + 308224);     //     1,568 B (NBUK+1)
    int*          offs    = (int*)(ws + 309888);     //   400,004 B (NN+1)
    float*        dis     = (float*)(ws + 710016);   //   400,000 B
    unsigned int* records = (unsigned int*)(ws + 1110144);  // 6,400,000 B
    ushort_t*     xwsb    = (ushort_t*)(ws + 7510144);      // 6,400,000 B
    const size_t WS_NEEDED = 13910144ull;

    if (ws_size >= WS_NEEDED) {
        hist_kernel<<<FILLB, 256, 0, stream>>>(col, histmat);
        colscan_kernel<<<NBUK, 256, 0, stream>>>(histmat, bsum);
        bscan_kernel<<<1, 512, 0, stream>>>(bsum, base);
        fill_kernel<<<FILLB, 256, 0, stream>>>(row, col, base, histmat, records);
        sort_kernel<<<NBUK, 256, 0, stream>>>(base, records, dis, offs);
        {
            int bl = (NN + 63) / 64;
            xw_kernel<<<bl, 256, 0, stream>>>(x, W, dis, xwsb);
        }
        {
            long long threads = (long long)NN * 64;
            int bl = (int)((threads + 255) / 256);
            aggregate_kernel<<<bl, 256, 0, stream>>>(offs, (const int*)records, dis, xwsb, b, out);
        }
    } else {
        // fallback: atomic scatter path
        int* deg = (int*)(ws + 0);
        float* dis2 = (float*)(ws + 400128);
        float* xw = (float*)(ws + 800256);
        hipMemsetAsync(deg, 0, NN * sizeof(int), stream);
        {
            int th = 256, bl = (NE + th - 1) / th;
            deg_count_kernel<<<bl, th, 0, stream>>>(col, deg);
        }
        {
            int th = 256, bl = (NN + th - 1) / th;
            dis_kernel<<<bl, th, 0, stream>>>(deg, dis2);
        }
        {
            long long total = (long long)NN * DOUT;
            int bl = (int)((total + 255) / 256);
            xw_init_kernel<<<bl, 256, 0, stream>>>(x, W, b, dis2, xw, out);
        }
        {
            long long total = (long long)NE * DOUT;
            int bl = (int)((total + 255) / 256);
            scatter_kernel<<<bl, 256, 0, stream>>>(row, col, dis2, xw, out);
        }
    }
}

// Round 8
// 112.236 us; speedup vs baseline: 1.3339x; 1.2292x over previous
//
#include <hip/hip_runtime.h>

#define NN 100000
#define NE 1600000
#define DIN 128
#define DOUT 32
#define NBUK 391     // ceil(NN/256) buckets of 256 nodes
#define FILLB 196    // edge chunks
#define CHUNK 8192   // edges per chunk (196*8192 >= NE)
#define CAP 8192     // max records per bucket staged in LDS (mean 4092, sd ~64)

typedef unsigned short ushort_t;
typedef unsigned int uint_t;
typedef _Float16 f16x8 __attribute__((ext_vector_type(8)));
typedef float f32x4 __attribute__((ext_vector_type(4)));

static __device__ __forceinline__ ushort_t f2h_u(float f) {
    _Float16 h = (_Float16)f;
    ushort_t u;
    __builtin_memcpy(&u, &h, 2);
    return u;
}
static __device__ __forceinline__ float h_lo(uint_t p) {
    ushort_t us = (ushort_t)(p & 0xffffu);
    _Float16 h;
    __builtin_memcpy(&h, &us, 2);
    return (float)h;
}
static __device__ __forceinline__ float h_hi(uint_t p) {
    ushort_t us = (ushort_t)(p >> 16);
    _Float16 h;
    __builtin_memcpy(&h, &us, 2);
    return (float)h;
}

// ===========================================================================
// k0: Wht[c][k] = f16(W[k][c])  (transposed fp16 weights, 8 KB)
// ===========================================================================
__global__ __launch_bounds__(256)
void wb_kernel(const float* __restrict__ W, ushort_t* __restrict__ Wht) {
    int i = blockIdx.x * 256 + threadIdx.x;
    if (i < DIN * DOUT) {
        int c = i >> 7;       // 0..31
        int k = i & 127;      // 0..127
        Wht[(size_t)c * DIN + k] = f2h_u(W[(size_t)k * DOUT + c]);
    }
}

// ===========================================================================
// k1: per-(chunk,bucket) histogram -> histmat[FILLB][NBUK]. LDS atomics only.
// ===========================================================================
__global__ __launch_bounds__(256)
void hist_kernel(const int* __restrict__ col, int* __restrict__ histmat) {
    __shared__ int h[NBUK];
    int t = threadIdx.x, blk = blockIdx.x;
    for (int b = t; b < NBUK; b += 256) h[b] = 0;
    __syncthreads();
    int e0 = blk * CHUNK, emax = min(e0 + CHUNK, NE);
    for (int e = e0 + t; e < emax; e += 256) atomicAdd(&h[col[e] >> 8], 1);
    __syncthreads();
    for (int b = t; b < NBUK; b += 256) histmat[(size_t)blk * NBUK + b] = h[b];
}

// ===========================================================================
// k2a: per-bucket exclusive scan over the 196 chunks (in place) + bucket totals
// ===========================================================================
__global__ __launch_bounds__(256)
void colscan_kernel(int* __restrict__ histmat, int* __restrict__ bsum) {
    __shared__ int s[256];
    int b = blockIdx.x, t = threadIdx.x;
    int v = (t < FILLB) ? histmat[(size_t)t * NBUK + b] : 0;
    s[t] = v;
    __syncthreads();
    for (int off = 1; off < 256; off <<= 1) {
        int u = (t >= off) ? s[t - off] : 0;
        __syncthreads();
        s[t] += u;
        __syncthreads();
    }
    if (t < FILLB) histmat[(size_t)t * NBUK + b] = s[t] - v;  // exclusive
    if (t == FILLB - 1) bsum[b] = s[t];
}

// ===========================================================================
// k2b: exclusive scan of bucket totals -> base[NBUK+1]
// ===========================================================================
__global__ void bscan_kernel(const int* __restrict__ bsum, int* __restrict__ base) {
    __shared__ int s[512];
    int t = threadIdx.x;
    int own = (t < NBUK) ? bsum[t] : 0;
    s[t] = own;
    __syncthreads();
    for (int off = 1; off < 512; off <<= 1) {
        int v = (t >= off) ? s[t - off] : 0;
        __syncthreads();
        s[t] += v;
        __syncthreads();
    }
    if (t < NBUK) {
        base[t] = s[t] - own;
        if (t == NBUK - 1) base[NBUK] = s[t];
    }
}

// ===========================================================================
// k3: fill records at deterministic positions (LDS cursors, no global atomics)
// record = (row << 8) | (col & 255)
// ===========================================================================
__global__ __launch_bounds__(256)
void fill_kernel(const int* __restrict__ row, const int* __restrict__ col,
                 const int* __restrict__ base, const int* __restrict__ histmat,
                 unsigned int* __restrict__ records) {
    __shared__ int lcur[NBUK];
    int t = threadIdx.x, blk = blockIdx.x;
    for (int b = t; b < NBUK; b += 256)
        lcur[b] = base[b] + histmat[(size_t)blk * NBUK + b];
    __syncthreads();
    int e0 = blk * CHUNK, emax = min(e0 + CHUNK, NE);
    for (int e = e0 + t; e < emax; e += 256) {
        int c = col[e];
        int slot = atomicAdd(&lcur[c >> 8], 1);
        records[slot] = ((unsigned int)row[e] << 8) | (unsigned int)(c & 255);
    }
}

// ===========================================================================
// k4: per-bucket sort (records -> grouped by node, in place), + deg -> dis,
// + per-node CSR offsets. All writes block-local / coalesced.
// ===========================================================================
__global__ __launch_bounds__(256)
void sort_kernel(const int* __restrict__ base, unsigned int* __restrict__ records,
                 float* __restrict__ dis, int* __restrict__ offs) {
    __shared__ unsigned int stage[CAP];  // 32 KB
    __shared__ int hist[256];
    __shared__ int sc[256];
    __shared__ int lcur[256];
    int b = blockIdx.x, t = threadIdx.x;
    int s = base[b], e = base[b + 1];
    int cnt = e - s;
    hist[t] = 0;
    for (int j = t; j < cnt; j += 256) stage[j] = records[s + j];
    __syncthreads();
    for (int j = t; j < cnt; j += 256) atomicAdd(&hist[stage[j] & 255u], 1);
    __syncthreads();
    int d = hist[t];
    sc[t] = d;
    __syncthreads();
    for (int off = 1; off < 256; off <<= 1) {
        int u = (t >= off) ? sc[t - off] : 0;
        __syncthreads();
        sc[t] += u;
        __syncthreads();
    }
    int excl = sc[t] - d;
    int n = (b << 8) + t;
    if (n < NN) {
        dis[n] = rsqrtf((float)(d + 1));
        offs[n] = s + excl;
        if (n == NN - 1) offs[NN] = e;
    }
    lcur[t] = excl;
    __syncthreads();
    for (int j = t; j < cnt; j += 256) {
        unsigned int rec = stage[j];
        int slot = atomicAdd(&lcur[rec & 255u], 1);
        records[s + slot] = rec >> 8;  // now plain src row id
    }
}

// ===========================================================================
// k5: xwsh[r] = f16( (x[r] @ W) * dis[r] )  via MFMA.
// One wave = 16 rows; 4 waves/block; 6250 waves total (NN = 6250*16 exactly).
// A frag: row = lane&15, k = (lane>>4)*8 + i  (8 contiguous fp32 -> f16)
// B frag: col = lane&15, same k run (16B load from transposed Wht[32][128])
// C/D:    col = lane&15, row = (lane>>4)*4 + reg
// Per wave: 8 x-loads (independent), 8 B-loads (L1-resident), 8 MFMA.
// ===========================================================================
__global__ __launch_bounds__(256)
void xw_kernel(const float* __restrict__ x, const ushort_t* __restrict__ Wht,
               const float* __restrict__ dis, ushort_t* __restrict__ xwsh) {
    int t = threadIdx.x;
    int wv = t >> 6, lane = t & 63;
    int wtile = blockIdx.x * 4 + wv;
    if (wtile >= NN / 16) return;          // uniform per wave
    int r0 = wtile * 16;
    int rowi = lane & 15;                  // A-row / B-col / D-col
    int kg = lane >> 4;                    // k-group (0..3)

    // B fragments: 2 N-tiles x 4 K-steps, 16B each from Wht
    f16x8 bfrag[2][4];
#pragma unroll
    for (int t2 = 0; t2 < 2; ++t2)
#pragma unroll
        for (int s = 0; s < 4; ++s)
            bfrag[t2][s] = *(const f16x8*)(Wht + (size_t)(t2 * 16 + rowi) * DIN + s * 32 + kg * 8);

    // A: row r0+rowi, 8 fp32 per K-step at k = s*32 + kg*8
    const float* __restrict__ xr = x + (size_t)(r0 + rowi) * DIN;
    float4 xa[8];
#pragma unroll
    for (int s = 0; s < 4; ++s) {
        xa[2 * s]     = *(const float4*)(xr + s * 32 + kg * 8);
        xa[2 * s + 1] = *(const float4*)(xr + s * 32 + kg * 8 + 4);
    }
    f16x8 afrag[4];
#pragma unroll
    for (int s = 0; s < 4; ++s) {
        f16x8 a;
        a[0] = (_Float16)xa[2 * s].x;     a[1] = (_Float16)xa[2 * s].y;
        a[2] = (_Float16)xa[2 * s].z;     a[3] = (_Float16)xa[2 * s].w;
        a[4] = (_Float16)xa[2 * s + 1].x; a[5] = (_Float16)xa[2 * s + 1].y;
        a[6] = (_Float16)xa[2 * s + 1].z; a[7] = (_Float16)xa[2 * s + 1].w;
        afrag[s] = a;
    }

    f32x4 acc0 = {0.f, 0.f, 0.f, 0.f};
    f32x4 acc1 = {0.f, 0.f, 0.f, 0.f};
#pragma unroll
    for (int s = 0; s < 4; ++s) {
        acc0 = __builtin_amdgcn_mfma_f32_16x16x32_f16(afrag[s], bfrag[0][s], acc0, 0, 0, 0);
        acc1 = __builtin_amdgcn_mfma_f32_16x16x32_f16(afrag[s], bfrag[1][s], acc1, 0, 0, 0);
    }

    // epilogue: D[row= kg*4+j][col= rowi]; scale by dis[row], store f16
#pragma unroll
    for (int j = 0; j < 4; ++j) {
        int orow = r0 + kg * 4 + j;
        float dv = dis[orow];
        xwsh[(size_t)orow * DOUT + rowi]      = f2h_u(acc0[j] * dv);
        xwsh[(size_t)orow * DOUT + 16 + rowi] = f2h_u(acc1[j] * dv);
    }
}

// ===========================================================================
// k6: per-node wave gather over f16 rows (64 B = 1 line per edge).
// lane = (slot 0..15, dhalf 0..3): 16 edges/iter, uint4 gather per lane;
// masked tail lanes dedup to one line. shfl_xor(4/8/16/32) reduce.
// ===========================================================================
__global__ __launch_bounds__(256)
void aggregate_kernel(const int* __restrict__ offs, const int* __restrict__ srcs,
                      const float* __restrict__ dis, const ushort_t* __restrict__ xwsh,
                      const float* __restrict__ bias, float* __restrict__ out) {
    int wid = (int)((blockIdx.x * blockDim.x + threadIdx.x) >> 6);
    if (wid >= NN) return;
    int lane = threadIdx.x & 63;
    int slot = lane >> 2;        // 0..15 edge slot
    int d0 = (lane & 3) << 3;    // 0,8,16,24
    int s = offs[wid], e = offs[wid + 1];
    float a[8] = {0.f, 0.f, 0.f, 0.f, 0.f, 0.f, 0.f, 0.f};
#pragma unroll 2
    for (int i = s; i < e; i += 16) {
        int j = i + slot;
        bool ok = j < e;
        int r = srcs[ok ? j : e - 1];
        uint4 u = *(const uint4*)(xwsh + (size_t)r * DOUT + d0);
        float m = ok ? 1.f : 0.f;
        a[0] += m * h_lo(u.x); a[1] += m * h_hi(u.x);
        a[2] += m * h_lo(u.y); a[3] += m * h_hi(u.y);
        a[4] += m * h_lo(u.z); a[5] += m * h_hi(u.z);
        a[6] += m * h_lo(u.w); a[7] += m * h_hi(u.w);
    }
#pragma unroll
    for (int msk = 4; msk <= 32; msk <<= 1) {
#pragma unroll
        for (int v = 0; v < 8; ++v) a[v] += __shfl_xor(a[v], msk, 64);
    }
    if (slot == 0) {
        uint4 su = *(const uint4*)(xwsh + (size_t)wid * DOUT + d0);  // self-loop
        a[0] += h_lo(su.x); a[1] += h_hi(su.x);
        a[2] += h_lo(su.y); a[3] += h_hi(su.y);
        a[4] += h_lo(su.z); a[5] += h_hi(su.z);
        a[6] += h_lo(su.w); a[7] += h_hi(su.w);
        float dc = dis[wid];
        float4 b0 = *(const float4*)(bias + d0);
        float4 b1 = *(const float4*)(bias + d0 + 4);
        float4 o0, o1;
        o0.x = dc * a[0] + b0.x; o0.y = dc * a[1] + b0.y;
        o0.z = dc * a[2] + b0.z; o0.w = dc * a[3] + b0.w;
        o1.x = dc * a[4] + b1.x; o1.y = dc * a[5] + b1.y;
        o1.z = dc * a[6] + b1.z; o1.w = dc * a[7] + b1.w;
        *(float4*)(out + (size_t)wid * DOUT + d0) = o0;
        *(float4*)(out + (size_t)wid * DOUT + d0 + 4) = o1;
    }
}

// ===========================================================================
// Fallback path (R1) if workspace is too small
// ===========================================================================
__global__ void deg_count_kernel(const int* __restrict__ col, int* __restrict__ deg) {
    int e = blockIdx.x * blockDim.x + threadIdx.x;
    if (e < NE) atomicAdd(&deg[col[e]], 1);
}
__global__ void dis_kernel(const int* __restrict__ deg, float* __restrict__ dis) {
    int i = blockIdx.x * blockDim.x + threadIdx.x;
    if (i < NN) dis[i] = rsqrtf((float)(deg[i] + 1));
}
__global__ void xw_init_kernel(const float* __restrict__ x, const float* __restrict__ W,
                               const float* __restrict__ b, const float* __restrict__ dis,
                               float* __restrict__ xw, float* __restrict__ out) {
    __shared__ float Ws[DIN * DOUT];
    for (int i = threadIdx.x; i < DIN * DOUT; i += blockDim.x) Ws[i] = W[i];
    __syncthreads();
    int idx = blockIdx.x * blockDim.x + threadIdx.x;
    if (idx >= NN * DOUT) return;
    int n = idx >> 5;
    int d = idx & (DOUT - 1);
    const float* xr = x + (long long)n * DIN;
    float acc = 0.f;
#pragma unroll
    for (int k = 0; k < DIN; ++k) acc += xr[k] * Ws[k * DOUT + d];
    xw[idx] = acc;
    float di = dis[n];
    out[idx] = di * di * acc + b[d];
}
__global__ void scatter_kernel(const int* __restrict__ row, const int* __restrict__ col,
                               const float* __restrict__ dis, const float* __restrict__ xw,
                               float* __restrict__ out) {
    long long idx = (long long)blockIdx.x * blockDim.x + threadIdx.x;
    if (idx >= (long long)NE * DOUT) return;
    int e = (int)(idx >> 5);
    int d = (int)(idx & (DOUT - 1));
    int r = row[e];
    int c = col[e];
    atomicAdd(&out[c * DOUT + d], dis[r] * dis[c] * xw[r * DOUT + d]);
}

// ===========================================================================
extern "C" void kernel_launch(void* const* d_in, const int* in_sizes, int n_in,
                              void* d_out, int out_size, void* d_ws, size_t ws_size,
                              hipStream_t stream) {
    const float* x  = (const float*)d_in[0];
    const int*   ei = (const int*)d_in[1];
    const float* W  = (const float*)d_in[2];
    const float* b  = (const float*)d_in[3];
    float* out = (float*)d_out;

    const int* row = ei;       // edge_index[0] = source
    const int* col = ei + NE;  // edge_index[1] = target

    char* ws = (char*)d_ws;
    int*          histmat = (int*)(ws + 0);          //   306,544 B
    int*          bsum    = (int*)(ws + 306560);     //     1,564 B
    int*          base    = (int*)(ws + 308224);     //     1,568 B (NBUK+1)
    int*          offs    = (int*)(ws + 309888);     //   400,004 B (NN+1)
    float*        dis     = (float*)(ws + 710016);   //   400,000 B
    unsigned int* records = (unsigned int*)(ws + 1110144);  // 6,400,000 B
    ushort_t*     xwsh    = (ushort_t*)(ws + 7510144);      // 6,400,000 B
    ushort_t*     Wht     = (ushort_t*)(ws + 13910144);     //     8,192 B
    const size_t WS_NEEDED = 13918336ull;

    if (ws_size >= WS_NEEDED) {
        wb_kernel<<<16, 256, 0, stream>>>(W, Wht);
        hist_kernel<<<FILLB, 256, 0, stream>>>(col, histmat);
        colscan_kernel<<<NBUK, 256, 0, stream>>>(histmat, bsum);
        bscan_kernel<<<1, 512, 0, stream>>>(bsum, base);
        fill_kernel<<<FILLB, 256, 0, stream>>>(row, col, base, histmat, records);
        sort_kernel<<<NBUK, 256, 0, stream>>>(base, records, dis, offs);
        {
            int bl = (NN / 16 + 3) / 4;    // 6250 waves, 4 per block
            xw_kernel<<<bl, 256, 0, stream>>>(x, Wht, dis, xwsh);
        }
        {
            long long threads = (long long)NN * 64;
            int bl = (int)((threads + 255) / 256);
            aggregate_kernel<<<bl, 256, 0, stream>>>(offs, (const int*)records, dis, xwsh, b, out);
        }
    } else {
        // fallback: atomic scatter path
        int* deg = (int*)(ws + 0);
        float* dis2 = (float*)(ws + 400128);
        float* xw = (float*)(ws + 800256);
        hipMemsetAsync(deg, 0, NN * sizeof(int), stream);
        {
            int th = 256, bl = (NE + th - 1) / th;
            deg_count_kernel<<<bl, th, 0, stream>>>(col, deg);
        }
        {
            int th = 256, bl = (NN + th - 1) / th;
            dis_kernel<<<bl, th, 0, stream>>>(deg, dis2);
        }
        {
            long long total = (long long)NN * DOUT;
            int bl = (int)((total + 255) / 256);
            xw_init_kernel<<<bl, 256, 0, stream>>>(x, W, b, dis2, xw, out);
        }
        {
            long long total = (long long)NE * DOUT;
            int bl = (int)((total + 255) / 256);
            scatter_kernel<<<bl, 256, 0, stream>>>(row, col, dis2, xw, out);
        }
    }
}